// Round 1
// baseline (364.524 us; speedup 1.0000x reference)
//
#include <hip/hip_runtime.h>

// WindowAttention: x(128,256,512) -> qkv -> windowed attn (epeg conv folded
// into Q; barrier-free main loop, online softmax, no spill) -> proj.
//
// GEMMs use the 256x256 8-phase schedule (T1 XCD-chunk + T2 both-sides LDS
// swizzle + T3/T4 counted-vmcnt pipeline + T5 setprio), BK=64, 8 waves,
// 128 KiB LDS double buffer, K=512 (NT=8 K-tiles).
//
// ws layout (bytes):
//   [0)          xbf   33,554,432  (x bf16; REUSED as attnout after gemm_qkv)
//   [33554432)   w1     1,572,864  (qkv_w bf16)
//   [35127296)   w2       524,288  (proj_w bf16)
//   [35651584)   qb    33,554,432  (q scaled (b,h,n,d); conv'd in place)
//   [69206016)   kb    33,554,432  ((b,h,m,d))
//   [102760448)  vb    33,554,432  (V row-major (b,h,n,d))

typedef unsigned short u16;
typedef unsigned int u32;
typedef __attribute__((ext_vector_type(8))) short short8;   // 8 bf16 (4 VGPRs)
typedef __attribute__((ext_vector_type(4))) float f32x4;

__device__ __forceinline__ u16 f2bf(float f) {
  union { float f; u32 u; } v; v.f = f;
  return (u16)((v.u + 0x7FFFu + ((v.u >> 16) & 1u)) >> 16);  // RNE
}
__device__ __forceinline__ float bf2f(u16 s) {
  union { u32 u; float f; } v; v.u = ((u32)s) << 16;
  return v.f;
}

__device__ __forceinline__ void gl2lds16(const u16* g, u16* l) {
  __builtin_amdgcn_global_load_lds((const __attribute__((address_space(1))) void*)g,
                                   (__attribute__((address_space(3))) void*)l, 16, 0, 0);
}

// fragment cell address (u16 units) with bank-spreading XOR swizzle (attn)
__device__ __forceinline__ int fragaddr(int frag, int lane) {
  return (frag * 64 + (lane ^ (frag & 7))) * 8;
}

// ---------------- fp32 -> bf16 conversion ------------------------------------
__global__ __launch_bounds__(256) void cvt_all(
    const float* __restrict__ x, const float* __restrict__ w1f,
    const float* __restrict__ w2f, u16* __restrict__ xo,
    u16* __restrict__ w1o, u16* __restrict__ w2o) {
  const int NX = 4194304, NW1 = 196608, NW2 = 65536;
  int i = blockIdx.x * 256 + threadIdx.x;
  const float* src; u16* dst; int j;
  if (i < NX)                  { src = x;   dst = xo;  j = i; }
  else if (i < NX + NW1)       { src = w1f; dst = w1o; j = i - NX; }
  else if (i < NX + NW1 + NW2) { src = w2f; dst = w2o; j = i - NX - NW1; }
  else return;
  float4 f = ((const float4*)src)[j];
  uint2 o;
  o.x = (u32)f2bf(f.x) | ((u32)f2bf(f.y) << 16);
  o.y = (u32)f2bf(f.z) | ((u32)f2bf(f.w) << 16);
  ((uint2*)dst)[j] = o;
}

// ---------------- 256x256 8-phase GEMM core: C = A[256x512] * B[256x512]^T ---
// LDS (u16 units, per buf p in {0,1} at p*32768):
//   [0,8192)      A k-half 0  (256 rows x 32 cols)
//   [8192,16384)  B k-half 0
//   [16384,24576) A k-half 1
//   [24576,32768) B k-half 1
// Within a region, row-major [256][32] with 16B-chunk swizzle:
//   chunk_lds = chunk_g ^ (row&3) ^ ((row>>2)&3)   (involution; applied on
//   the GLOBAL source for staging, and on the ds_read address).
// Half-tile stream h = 4*T + {0:Ak0,1:Bk0,2:Ak1,3:Bk1}; stage(phase f)=h=f+5;
// 2 global_load_lds per thread per half. Steady-state waits vmcnt(6)
// (3 halves in flight), drain 6->4->0 at the stream tail (NT=8).
__device__ __forceinline__ void gemm256_core(
    const u16* __restrict__ A, const u16* __restrict__ B,
    int m0, int n0, u16* lds, f32x4 acc[8][4]) {
  const int NT = 8;                       // K = 512, BK = 64
  int tid = threadIdx.x, wave = tid >> 6, lane = tid & 63;
  int wm = wave >> 2, wn = wave & 3;

  // staging constants (2 x 16B chunks per thread per half-tile)
  int ch0 = tid, ch1 = tid + 512;
  int row0 = ch0 >> 2, row1 = ch1 >> 2;
  int cg0 = (ch0 & 3) ^ (row0 & 3) ^ ((row0 >> 2) & 3);
  int cg1 = (ch1 & 3) ^ (row1 & 3) ^ ((row1 >> 2) & 3);
  const u16* Ag0 = A + (size_t)(m0 + row0) * 512 + cg0 * 8;
  const u16* Ag1 = A + (size_t)(m0 + row1) * 512 + cg1 * 8;
  const u16* Bg0 = B + (size_t)(n0 + row0) * 512 + cg0 * 8;
  const u16* Bg1 = B + (size_t)(n0 + row1) * 512 + cg1 * 8;
  int ldsu0 = wave * 64 * 8;              // HW adds lane*16B
  int ldsu1 = (512 + wave * 64) * 8;

  // fragment read offset: row (lane&15), swizzled 16B chunk (lane>>4)
  int frag_off = (lane & 15) * 32 +
                 (((lane >> 4) ^ (lane & 3) ^ ((lane >> 2) & 3)) << 3);
  int abase = wm * 4096 + frag_off;        // + mf*512 + kh*16384 + p*32768
  int bbase = 8192 + wn * 2048 + frag_off; // + nf*512 + kh*16384 + p*32768

#define STAGE(h)                                                             \
  do {                                                                       \
    if ((h) < NT * 4) {                                                      \
      int T_ = (h) >> 2, kh_ = ((h) >> 1) & 1, isB_ = (h) & 1;               \
      int ko_ = T_ * 64 + kh_ * 32;                                          \
      u16* d_ = lds + (T_ & 1) * 32768 + kh_ * 16384 + isB_ * 8192;          \
      gl2lds16((isB_ ? Bg0 : Ag0) + ko_, d_ + ldsu0);                        \
      gl2lds16((isB_ ? Bg1 : Ag1) + ko_, d_ + ldsu1);                        \
    }                                                                        \
  } while (0)

#define LDA(dst, mf, kh, p)                                                  \
  dst = *(const short8*)(lds + (p) * 32768 + (kh) * 16384 + abase + (mf) * 512)
#define LDB(dst, nf, kh, p)                                                  \
  dst = *(const short8*)(lds + (p) * 32768 + (kh) * 16384 + bbase + (nf) * 512)

#define MM16(M0)                                                                                   \
  __builtin_amdgcn_s_setprio(1);                                                                   \
  acc[(M0)+0][0] = __builtin_amdgcn_mfma_f32_16x16x32_bf16(a0, b0, acc[(M0)+0][0], 0, 0, 0);       \
  acc[(M0)+0][1] = __builtin_amdgcn_mfma_f32_16x16x32_bf16(a0, b1, acc[(M0)+0][1], 0, 0, 0);       \
  acc[(M0)+0][2] = __builtin_amdgcn_mfma_f32_16x16x32_bf16(a0, b2, acc[(M0)+0][2], 0, 0, 0);       \
  acc[(M0)+0][3] = __builtin_amdgcn_mfma_f32_16x16x32_bf16(a0, b3, acc[(M0)+0][3], 0, 0, 0);       \
  acc[(M0)+1][0] = __builtin_amdgcn_mfma_f32_16x16x32_bf16(a1, b0, acc[(M0)+1][0], 0, 0, 0);       \
  acc[(M0)+1][1] = __builtin_amdgcn_mfma_f32_16x16x32_bf16(a1, b1, acc[(M0)+1][1], 0, 0, 0);       \
  acc[(M0)+1][2] = __builtin_amdgcn_mfma_f32_16x16x32_bf16(a1, b2, acc[(M0)+1][2], 0, 0, 0);       \
  acc[(M0)+1][3] = __builtin_amdgcn_mfma_f32_16x16x32_bf16(a1, b3, acc[(M0)+1][3], 0, 0, 0);       \
  acc[(M0)+2][0] = __builtin_amdgcn_mfma_f32_16x16x32_bf16(a2, b0, acc[(M0)+2][0], 0, 0, 0);       \
  acc[(M0)+2][1] = __builtin_amdgcn_mfma_f32_16x16x32_bf16(a2, b1, acc[(M0)+2][1], 0, 0, 0);       \
  acc[(M0)+2][2] = __builtin_amdgcn_mfma_f32_16x16x32_bf16(a2, b2, acc[(M0)+2][2], 0, 0, 0);       \
  acc[(M0)+2][3] = __builtin_amdgcn_mfma_f32_16x16x32_bf16(a2, b3, acc[(M0)+2][3], 0, 0, 0);       \
  acc[(M0)+3][0] = __builtin_amdgcn_mfma_f32_16x16x32_bf16(a3, b0, acc[(M0)+3][0], 0, 0, 0);       \
  acc[(M0)+3][1] = __builtin_amdgcn_mfma_f32_16x16x32_bf16(a3, b1, acc[(M0)+3][1], 0, 0, 0);       \
  acc[(M0)+3][2] = __builtin_amdgcn_mfma_f32_16x16x32_bf16(a3, b2, acc[(M0)+3][2], 0, 0, 0);       \
  acc[(M0)+3][3] = __builtin_amdgcn_mfma_f32_16x16x32_bf16(a3, b3, acc[(M0)+3][3], 0, 0, 0);       \
  __builtin_amdgcn_s_setprio(0)

  // ---- prologue: stage halves 0..4, publish h0,h1 (vmcnt: 10 out -> 6) ----
  STAGE(0); STAGE(1); STAGE(2); STAGE(3); STAGE(4);
  asm volatile("s_waitcnt vmcnt(6)" ::: "memory");
  __builtin_amdgcn_s_barrier();

#pragma unroll 1
  for (int kt = 0; kt < NT; ++kt) {
    int p = kt & 1;
    int hb = kt * 4 + 5;
    short8 a0, a1, a2, a3, b0, b1, b2, b3;
    // ---- phase 0: kh=0, mf 0-3 (+ B frags kh=0) ----
    LDA(a0, 0, 0, p); LDA(a1, 1, 0, p); LDA(a2, 2, 0, p); LDA(a3, 3, 0, p);
    LDB(b0, 0, 0, p); LDB(b1, 1, 0, p); LDB(b2, 2, 0, p); LDB(b3, 3, 0, p);
    STAGE(hb);
    __builtin_amdgcn_s_barrier();
    asm volatile("s_waitcnt lgkmcnt(0)" ::: "memory");
    MM16(0);
    __builtin_amdgcn_s_barrier();
    // ---- phase 1: kh=0, mf 4-7; reuse b0-b3 ----
    LDA(a0, 4, 0, p); LDA(a1, 5, 0, p); LDA(a2, 6, 0, p); LDA(a3, 7, 0, p);
    STAGE(hb + 1);
    __builtin_amdgcn_s_barrier();
    asm volatile("s_waitcnt lgkmcnt(0)" ::: "memory");
    MM16(4);
    if (kt == NT - 1) asm volatile("s_waitcnt vmcnt(0)" ::: "memory");
    else              asm volatile("s_waitcnt vmcnt(6)" ::: "memory");
    __builtin_amdgcn_s_barrier();
    // ---- phase 2: kh=1, mf 0-3 (+ B frags kh=1) ----
    LDA(a0, 0, 1, p); LDA(a1, 1, 1, p); LDA(a2, 2, 1, p); LDA(a3, 3, 1, p);
    LDB(b0, 0, 1, p); LDB(b1, 1, 1, p); LDB(b2, 2, 1, p); LDB(b3, 3, 1, p);
    STAGE(hb + 2);
    __builtin_amdgcn_s_barrier();
    asm volatile("s_waitcnt lgkmcnt(0)" ::: "memory");
    MM16(0);
    __builtin_amdgcn_s_barrier();
    // ---- phase 3: kh=1, mf 4-7 ----
    LDA(a0, 4, 1, p); LDA(a1, 5, 1, p); LDA(a2, 6, 1, p); LDA(a3, 7, 1, p);
    STAGE(hb + 3);
    __builtin_amdgcn_s_barrier();
    asm volatile("s_waitcnt lgkmcnt(0)" ::: "memory");
    MM16(4);
    if (kt == NT - 2)     asm volatile("s_waitcnt vmcnt(4)" ::: "memory");
    else if (kt < NT - 2) asm volatile("s_waitcnt vmcnt(6)" ::: "memory");
    __builtin_amdgcn_s_barrier();
  }
#undef STAGE
#undef LDA
#undef LDB
#undef MM16
}

// ---------------- GEMM1: qkv = x @ qkv_w^T + b; scatter q(scaled)/k/v --------
__global__ __launch_bounds__(512, 2) void gemm_qkv256(
    const u16* __restrict__ A, const u16* __restrict__ B,
    const float* __restrict__ qkvb, u16* __restrict__ qb,
    u16* __restrict__ kb, u16* __restrict__ vb) {
  __shared__ __align__(16) u16 lds[65536];   // 128 KiB
  f32x4 acc[8][4];
#pragma unroll
  for (int a = 0; a < 8; ++a)
#pragma unroll
    for (int c = 0; c < 4; ++c) acc[a][c] = (f32x4){0.f, 0.f, 0.f, 0.f};
  // XCD-chunked bijective swizzle (768 % 8 == 0): XCD k gets M-panels
  // [16k,16k+16) x all 6 N-blocks consecutively -> A-panel L2 reuse.
  int bid = blockIdx.x;
  int wg = (bid & 7) * 96 + (bid >> 3);
  int m0 = (wg / 6) * 256, n0 = (wg % 6) * 256;
  gemm256_core(A, B, m0, n0, lds, acc);
  int tid = threadIdx.x, wave = tid >> 6, lane = tid & 63;
  int wm = wave >> 2, wn = wave & 3;
#pragma unroll
  for (int nf = 0; nf < 4; ++nf) {
    int c = n0 + wn * 64 + nf * 16 + (lane & 15);
    float bv = qkvb[c];
    int which = c >> 9, cc = c & 511, h = cc >> 6, d = cc & 63;
#pragma unroll
    for (int mf = 0; mf < 8; ++mf) {
      int rbase = m0 + wm * 128 + mf * 16 + (lane >> 4) * 4;
#pragma unroll
      for (int i = 0; i < 4; ++i) {
        int r = rbase + i;
        int b = r >> 8, n = r & 255;
        float v = acc[mf][nf][i] + bv;
        size_t idx = ((size_t)(b * 8 + h) * 256 + n) * 64 + d;
        if (which == 0)      qb[idx] = f2bf(v * 0.125f);
        else if (which == 1) kb[idx] = f2bf(v);
        else                 vb[idx] = f2bf(v);
      }
    }
  }
}

// ---------------- GEMM2: out = attnout @ proj_w^T + proj_b (fp32 out) --------
__global__ __launch_bounds__(512, 2) void gemm_proj256(
    const u16* __restrict__ A, const u16* __restrict__ B,
    const float* __restrict__ pb, float* __restrict__ out) {
  __shared__ __align__(16) u16 lds[65536];   // 128 KiB
  f32x4 acc[8][4];
#pragma unroll
  for (int a = 0; a < 8; ++a)
#pragma unroll
    for (int c = 0; c < 4; ++c) acc[a][c] = (f32x4){0.f, 0.f, 0.f, 0.f};
  int bid = blockIdx.x;
  int wg = (bid & 7) * 32 + (bid >> 3);      // 256 % 8 == 0, bijective
  int m0 = (wg >> 1) * 256, n0 = (wg & 1) * 256;
  gemm256_core(A, B, m0, n0, lds, acc);
  int tid = threadIdx.x, wave = tid >> 6, lane = tid & 63;
  int wm = wave >> 2, wn = wave & 3;
#pragma unroll
  for (int nf = 0; nf < 4; ++nf) {
    int c = n0 + wn * 64 + nf * 16 + (lane & 15);
    float bv = pb[c];
#pragma unroll
    for (int mf = 0; mf < 8; ++mf) {
      int rbase = m0 + wm * 128 + mf * 16 + (lane >> 4) * 4;
#pragma unroll
      for (int i = 0; i < 4; ++i)
        out[(size_t)(rbase + i) * 512 + c] = acc[mf][nf][i] + bv;
    }
  }
}

// ---------------- qconv: Q' = Q + conv15_n(Q), in place per (b,h) window -----
__global__ __launch_bounds__(256) void qconv(u16* __restrict__ qb,
                                             const float* __restrict__ pe_w) {
  __shared__ __align__(16) u16 Ql[256 * 72];
  __shared__ float w[15];
  int bh = blockIdx.x, h = bh & 7, tid = threadIdx.x;
  const uint4* src = (const uint4*)(qb + (size_t)bh * 16384);
#pragma unroll
  for (int it = 0; it < 8; ++it) {
    int idx = tid + it * 256;
    int row = idx >> 3, c = (idx & 7) * 8;
    *(uint4*)(Ql + row * 72 + c) = src[idx];
  }
  if (tid < 15) w[tid] = pe_w[h * 15 + tid] + (tid == 7 ? 1.f : 0.f);  // identity folded
  __syncthreads();
  int dg = (tid & 15) * 4, nb4 = tid >> 4;
  uint2* dst = (uint2*)(qb + (size_t)bh * 16384);
#pragma unroll
  for (int i = 0; i < 16; ++i) {
    int n = nb4 + i * 16;
    float a0 = 0.f, a1 = 0.f, a2 = 0.f, a3 = 0.f;
#pragma unroll
    for (int t = 0; t < 15; ++t) {
      int nn = n + t - 7;
      if (nn < 0 || nn > 255) continue;
      uint2 rv = *(const uint2*)(Ql + nn * 72 + dg);
      float wt = w[t];
      a0 += wt * bf2f(rv.x & 0xffff); a1 += wt * bf2f(rv.x >> 16);
      a2 += wt * bf2f(rv.y & 0xffff); a3 += wt * bf2f(rv.y >> 16);
    }
    uint2 pv;
    pv.x = (u32)f2bf(a0) | ((u32)f2bf(a1) << 16);
    pv.y = (u32)f2bf(a2) | ((u32)f2bf(a3) << 16);
    dst[(n * 64 + dg) >> 2] = pv;
  }
}

// ---------------- attention: 1 wg (512 thr) per (b,h); barrier-free loop -----
// LDS: KfPs 42K (Kf 32K + Ps 10K; doubles as Vtmp during staging) + Vf 32K +
// bias 3.8K = ~79.6K -> 2 wg/CU. Online softmax over 2 column halves keeps
// regs ~100 (no spill; launch_bounds(512,2) cannot force one).
__global__ __launch_bounds__(512, 2) void attn_win(
    const u16* __restrict__ qb, const u16* __restrict__ kb,
    const u16* __restrict__ vb, const float* __restrict__ pe_b,
    const float* __restrict__ rpb, u16* __restrict__ attnout) {
  __shared__ __align__(16) u16 KfPs[21504];   // [0,16384)=Kf, [16384,21504)=Ps
  __shared__ __align__(16) u16 Vf[16384];     // 32 frags (dt,km), fragment-ordered
  __shared__ float biasl[961];
  __shared__ float pebs;

  int bh = blockIdx.x, b = bh >> 3, h = bh & 7;
  int tid = threadIdx.x, wave = tid >> 6, lane = tid & 63;
  int cx = lane & 15, g = lane >> 4;

  const uint4* kg = (const uint4*)(kb + (size_t)bh * 16384);
  const uint4* vg = (const uint4*)(vb + (size_t)bh * 16384);

  // K prefetch into registers (Kf region is occupied by Vtmp until Vf built)
  uint4 kreg[4];
#pragma unroll
  for (int it = 0; it < 4; ++it) kreg[it] = kg[tid + it * 512];

  // ---- stage V rows -> Vtmp (stride 68, bank-spread) + bias ----
  u16* Vtmp = KfPs;
#pragma unroll
  for (int it = 0; it < 4; ++it) {
    int idx = tid + it * 512;
    uint4 v = vg[idx];
    int row = idx >> 3, c8 = (idx & 7) * 8;
    *(uint2*)(Vtmp + row * 68 + c8)     = make_uint2(v.x, v.y);
    *(uint2*)(Vtmp + row * 68 + c8 + 4) = make_uint2(v.z, v.w);
  }
  for (int i = tid; i < 961; i += 512) biasl[i] = rpb[i * 8 + h];
  if (tid == 0) pebs = pe_b[h];
  __syncthreads();

  // ---- build Vf fragments (transpose): frag(dt,km), lane holds V[m..m+7][d] --
#pragma unroll
  for (int it = 0; it < 4; ++it) {
    int o = tid + it * 512;
    int frag = o >> 6, lanep = o & 63;
    int d = (frag >> 3) * 16 + (lanep & 15);
    int mb = (frag & 7) * 32 + (lanep >> 4) * 8;
    uint4 pk;
    pk.x = (u32)Vtmp[(mb + 0) * 68 + d] | ((u32)Vtmp[(mb + 1) * 68 + d] << 16);
    pk.y = (u32)Vtmp[(mb + 2) * 68 + d] | ((u32)Vtmp[(mb + 3) * 68 + d] << 16);
    pk.z = (u32)Vtmp[(mb + 4) * 68 + d] | ((u32)Vtmp[(mb + 5) * 68 + d] << 16);
    pk.w = (u32)Vtmp[(mb + 6) * 68 + d] | ((u32)Vtmp[(mb + 7) * 68 + d] << 16);
    *(uint4*)(Vf + (frag * 64 + (lanep ^ (frag & 7))) * 8) = pk;
  }
  __syncthreads();

  // ---- write K fragments from registers ----
  u16* Kf = KfPs;
#pragma unroll
  for (int it = 0; it < 4; ++it) {
    int idx = tid + it * 512;
    int n = idx >> 3, k8 = idx & 7;
    int frag = (n >> 4) * 2 + (k8 >> 2);
    int lanep = (n & 15) + 16 * (k8 & 3);
    *(uint4*)(Kf + (frag * 64 + (lanep ^ (frag & 7))) * 8) = kreg[it];
  }
  __syncthreads();   // last barrier — main loop is barrier-free

  u16* Psw = KfPs + 16384 + wave * 640;
  const u16* qgb = qb + (size_t)bh * 16384;

  for (int it2 = 0; it2 < 2; ++it2) {
    int qbase = it2 * 128 + wave * 16;
    const u16* qg = qgb + qbase * 64;
    short8 qf0 = *(const short8*)(qg + cx * 64 + g * 8);
    short8 qf1 = *(const short8*)(qg + cx * 64 + 32 + g * 8);

    float m_run[4] = {-1e30f, -1e30f, -1e30f, -1e30f};
    float l_run[4] = {0.f, 0.f, 0.f, 0.f};
    f32x4 oacc[4];
#pragma unroll
    for (int dt = 0; dt < 4; ++dt) oacc[dt] = (f32x4){0.f, 0.f, 0.f, 0.f};

#pragma unroll
    for (int c = 0; c < 2; ++c) {
      // ---- QK^T over this 128-column half ----
      f32x4 acc[8];
#pragma unroll
      for (int mt = 0; mt < 8; ++mt) acc[mt] = (f32x4){0.f, 0.f, 0.f, 0.f};
#pragma unroll
      for (int mt = 0; mt < 8; ++mt) {
        int fr = (c * 8 + mt) * 2;
        short8 k0 = *(const short8*)(Kf + fragaddr(fr, lane));
        short8 k1 = *(const short8*)(Kf + fragaddr(fr + 1, lane));
        acc[mt] = __builtin_amdgcn_mfma_f32_16x16x32_bf16(qf0, k0, acc[mt], 0, 0, 0);
        acc[mt] = __builtin_amdgcn_mfma_f32_16x16x32_bf16(qf1, k1, acc[mt], 0, 0, 0);
      }

      // ---- bias + online softmax update (in-wave, no barriers) ----
      float alpha4[4];
#pragma unroll
      for (int i = 0; i < 4; ++i) {
        int qtok = qbase + g * 4 + i;
        int bbase = ((qtok >> 4) - c * 8 + 15) * 31 + (qtok & 15) - cx + 15;
#pragma unroll
        for (int mt = 0; mt < 8; ++mt) acc[mt][i] += pebs + biasl[bbase - 31 * mt];
        float mx = acc[0][i];
#pragma unroll
        for (int mt = 1; mt < 8; ++mt) mx = fmaxf(mx, acc[mt][i]);
        mx = fmaxf(mx, __shfl_xor(mx, 1));
        mx = fmaxf(mx, __shfl_xor(mx, 2));
        mx = fmaxf(mx, __shfl_xor(mx, 4));
        mx = fmaxf(mx, __shfl_xor(mx, 8));
        float mnew = fmaxf(m_run[i], mx);
        float al = __expf(m_run[i] - mnew);
        float s = 0.f;
#pragma unroll
        for (int mt = 0; mt < 8; ++mt) {
          float e = __expf(acc[mt][i] - mnew);
          acc[mt][i] = e; s += e;
        }
        s += __shfl_xor(s, 1);
        s += __shfl_xor(s, 2);
        s += __shfl_xor(s, 4);
        s += __shfl_xor(s, 8);
        l_run[i] = l_run[i] * al + s;
        m_run[i] = mnew;
        alpha4[i] = al;
      }
#pragma unroll
      for (int dt = 0; dt < 4; ++dt)
#pragma unroll
        for (int i = 0; i < 4; ++i) oacc[dt][i] *= alpha4[i];

      // ---- PV via per-wave scratch (in-wave LDS ordering) ----
#pragma unroll
      for (int kk = 0; kk < 4; ++kk) {
#pragma unroll
        for (int t2 = 0; t2 < 2; ++t2)
#pragma unroll
          for (int i = 0; i < 4; ++i)
            Psw[(g * 4 + i) * 40 + t2 * 16 + cx] = f2bf(acc[kk * 2 + t2][i]);
        short8 pa = *(const short8*)(Psw + cx * 40 + g * 8);
#pragma unroll
        for (int dt = 0; dt < 4; ++dt) {
          short8 vf = *(const short8*)(Vf + fragaddr(dt * 8 + c * 4 + kk, lane));
          oacc[dt] = __builtin_amdgcn_mfma_f32_16x16x32_bf16(pa, vf, oacc[dt], 0, 0, 0);
        }
      }
    }

    // ---- epilogue: normalize + store ----
    float inv4[4];
#pragma unroll
    for (int i = 0; i < 4; ++i) inv4[i] = 1.f / l_run[i];
#pragma unroll
    for (int dt = 0; dt < 4; ++dt)
#pragma unroll
      for (int i = 0; i < 4; ++i)
        attnout[((size_t)b * 256 + qbase + g * 4 + i) * 512 + h * 64 + dt * 16 + cx]
            = f2bf(oacc[dt][i] * inv4[i]);
  }
}

extern "C" void kernel_launch(void* const* d_in, const int* in_sizes, int n_in,
                              void* d_out, int out_size, void* d_ws, size_t ws_size,
                              hipStream_t stream) {
  const float* x      = (const float*)d_in[0];
  const float* qkv_w  = (const float*)d_in[1];
  const float* qkv_b  = (const float*)d_in[2];
  const float* pe_w   = (const float*)d_in[3];
  const float* pe_b   = (const float*)d_in[4];
  const float* rpb    = (const float*)d_in[5];
  const float* proj_w = (const float*)d_in[6];
  const float* proj_b = (const float*)d_in[7];
  float* out = (float*)d_out;
  char* ws = (char*)d_ws;

  size_t off = 0;
  u16* xbf = (u16*)(ws + off); off += (size_t)16777216 * 2;  // also attnout
  u16* w1  = (u16*)(ws + off); off += (size_t)786432 * 2;
  u16* w2  = (u16*)(ws + off); off += (size_t)262144 * 2;
  u16* qb  = (u16*)(ws + off); off += (size_t)16777216 * 2;
  u16* kb  = (u16*)(ws + off); off += (size_t)16777216 * 2;
  u16* vb  = (u16*)(ws + off); off += (size_t)16777216 * 2;

  hipLaunchKernelGGL(cvt_all, dim3(17408), dim3(256), 0, stream,
                     x, qkv_w, proj_w, xbf, w1, w2);
  hipLaunchKernelGGL(gemm_qkv256, dim3(768), dim3(512), 0, stream,
                     xbf, w1, qkv_b, qb, kb, vb);
  hipLaunchKernelGGL(qconv, dim3(1024), dim3(256), 0, stream, qb, pe_w);
  hipLaunchKernelGGL(attn_win, dim3(1024), dim3(512), 0, stream,
                     qb, kb, vb, pe_b, rpb, xbf);
  hipLaunchKernelGGL(gemm_proj256, dim3(256), dim3(512), 0, stream,
                     xbf, w2, proj_b, out);
}

// Round 2
// 323.863 us; speedup vs baseline: 1.1255x; 1.1255x over previous
//
#include <hip/hip_runtime.h>

// WindowAttention: x(128,256,512) -> qkv -> windowed attn (epeg conv folded
// into Q; barrier-free main loop, online softmax, no spill) -> proj.
//
// GEMMs use the 256x256 8-phase schedule (T1 XCD-chunk + T2 both-sides LDS
// swizzle + T3/T4 counted-vmcnt pipeline + T5 setprio), BK=64, 8 waves,
// 128 KiB LDS double buffer, K=512 (NT=8 K-tiles).
// gemm_qkv epilogue: C-tile staged in LDS (reused post-loop), stored as
// contiguous 32KB (b,h,n,d) slabs with dwordx4 -> no partial-line writes.
//
// ws layout (bytes):
//   [0)          xbf   33,554,432  (x bf16; REUSED as attnout after gemm_qkv)
//   [33554432)   w1     1,572,864  (qkv_w bf16)
//   [35127296)   w2       524,288  (proj_w bf16)
//   [35651584)   qb    33,554,432  (q scaled (b,h,n,d); conv'd in place)
//   [69206016)   kb    33,554,432  ((b,h,m,d))
//   [102760448)  vb    33,554,432  (V row-major (b,h,n,d))

typedef unsigned short u16;
typedef unsigned int u32;
typedef __attribute__((ext_vector_type(8))) short short8;   // 8 bf16 (4 VGPRs)
typedef __attribute__((ext_vector_type(4))) float f32x4;

__device__ __forceinline__ u16 f2bf(float f) {
  union { float f; u32 u; } v; v.f = f;
  return (u16)((v.u + 0x7FFFu + ((v.u >> 16) & 1u)) >> 16);  // RNE
}
__device__ __forceinline__ float bf2f(u16 s) {
  union { u32 u; float f; } v; v.u = ((u32)s) << 16;
  return v.f;
}

__device__ __forceinline__ void gl2lds16(const u16* g, u16* l) {
  __builtin_amdgcn_global_load_lds((const __attribute__((address_space(1))) void*)g,
                                   (__attribute__((address_space(3))) void*)l, 16, 0, 0);
}

// fragment cell address (u16 units) with bank-spreading XOR swizzle (attn)
__device__ __forceinline__ int fragaddr(int frag, int lane) {
  return (frag * 64 + (lane ^ (frag & 7))) * 8;
}

// ---------------- fp32 -> bf16 conversion ------------------------------------
__global__ __launch_bounds__(256) void cvt_all(
    const float* __restrict__ x, const float* __restrict__ w1f,
    const float* __restrict__ w2f, u16* __restrict__ xo,
    u16* __restrict__ w1o, u16* __restrict__ w2o) {
  const int NX = 4194304, NW1 = 196608, NW2 = 65536;
  int i = blockIdx.x * 256 + threadIdx.x;
  const float* src; u16* dst; int j;
  if (i < NX)                  { src = x;   dst = xo;  j = i; }
  else if (i < NX + NW1)       { src = w1f; dst = w1o; j = i - NX; }
  else if (i < NX + NW1 + NW2) { src = w2f; dst = w2o; j = i - NX - NW1; }
  else return;
  float4 f = ((const float4*)src)[j];
  uint2 o;
  o.x = (u32)f2bf(f.x) | ((u32)f2bf(f.y) << 16);
  o.y = (u32)f2bf(f.z) | ((u32)f2bf(f.w) << 16);
  ((uint2*)dst)[j] = o;
}

// ---------------- 256x256 8-phase GEMM core: C = A[256x512] * B[256x512]^T ---
// LDS (u16 units, per buf p in {0,1} at p*32768):
//   [0,8192)      A k-half 0  (256 rows x 32 cols)
//   [8192,16384)  B k-half 0
//   [16384,24576) A k-half 1
//   [24576,32768) B k-half 1
// Within a region, row-major [256][32] with 16B-chunk swizzle:
//   chunk_lds = chunk_g ^ (row&3) ^ ((row>>2)&3)   (involution; applied on
//   the GLOBAL source for staging, and on the ds_read address).
// Half-tile stream h = 4*T + {0:Ak0,1:Bk0,2:Ak1,3:Bk1}; stage(phase f)=h=f+5;
// 2 global_load_lds per thread per half. Steady-state waits vmcnt(6)
// (3 halves in flight), drain 6->4->0 at the stream tail (NT=8).
// On exit: vmcnt == 0 (drained at kt=NT-1 phase1) -> LDS reusable after barrier.
__device__ __forceinline__ void gemm256_core(
    const u16* __restrict__ A, const u16* __restrict__ B,
    int m0, int n0, u16* lds, f32x4 acc[8][4]) {
  const int NT = 8;                       // K = 512, BK = 64
  int tid = threadIdx.x, wave = tid >> 6, lane = tid & 63;
  int wm = wave >> 2, wn = wave & 3;

  // staging constants (2 x 16B chunks per thread per half-tile)
  int ch0 = tid, ch1 = tid + 512;
  int row0 = ch0 >> 2, row1 = ch1 >> 2;
  int cg0 = (ch0 & 3) ^ (row0 & 3) ^ ((row0 >> 2) & 3);
  int cg1 = (ch1 & 3) ^ (row1 & 3) ^ ((row1 >> 2) & 3);
  const u16* Ag0 = A + (size_t)(m0 + row0) * 512 + cg0 * 8;
  const u16* Ag1 = A + (size_t)(m0 + row1) * 512 + cg1 * 8;
  const u16* Bg0 = B + (size_t)(n0 + row0) * 512 + cg0 * 8;
  const u16* Bg1 = B + (size_t)(n0 + row1) * 512 + cg1 * 8;
  int ldsu0 = wave * 64 * 8;              // HW adds lane*16B
  int ldsu1 = (512 + wave * 64) * 8;

  // fragment read offset: row (lane&15), swizzled 16B chunk (lane>>4)
  int frag_off = (lane & 15) * 32 +
                 (((lane >> 4) ^ (lane & 3) ^ ((lane >> 2) & 3)) << 3);
  int abase = wm * 4096 + frag_off;        // + mf*512 + kh*16384 + p*32768
  int bbase = 8192 + wn * 2048 + frag_off; // + nf*512 + kh*16384 + p*32768

#define STAGE(h)                                                             \
  do {                                                                       \
    if ((h) < NT * 4) {                                                      \
      int T_ = (h) >> 2, kh_ = ((h) >> 1) & 1, isB_ = (h) & 1;               \
      int ko_ = T_ * 64 + kh_ * 32;                                          \
      u16* d_ = lds + (T_ & 1) * 32768 + kh_ * 16384 + isB_ * 8192;          \
      gl2lds16((isB_ ? Bg0 : Ag0) + ko_, d_ + ldsu0);                        \
      gl2lds16((isB_ ? Bg1 : Ag1) + ko_, d_ + ldsu1);                        \
    }                                                                        \
  } while (0)

#define LDA(dst, mf, kh, p)                                                  \
  dst = *(const short8*)(lds + (p) * 32768 + (kh) * 16384 + abase + (mf) * 512)
#define LDB(dst, nf, kh, p)                                                  \
  dst = *(const short8*)(lds + (p) * 32768 + (kh) * 16384 + bbase + (nf) * 512)

#define MM16(M0)                                                                                   \
  __builtin_amdgcn_s_setprio(1);                                                                   \
  acc[(M0)+0][0] = __builtin_amdgcn_mfma_f32_16x16x32_bf16(a0, b0, acc[(M0)+0][0], 0, 0, 0);       \
  acc[(M0)+0][1] = __builtin_amdgcn_mfma_f32_16x16x32_bf16(a0, b1, acc[(M0)+0][1], 0, 0, 0);       \
  acc[(M0)+0][2] = __builtin_amdgcn_mfma_f32_16x16x32_bf16(a0, b2, acc[(M0)+0][2], 0, 0, 0);       \
  acc[(M0)+0][3] = __builtin_amdgcn_mfma_f32_16x16x32_bf16(a0, b3, acc[(M0)+0][3], 0, 0, 0);       \
  acc[(M0)+1][0] = __builtin_amdgcn_mfma_f32_16x16x32_bf16(a1, b0, acc[(M0)+1][0], 0, 0, 0);       \
  acc[(M0)+1][1] = __builtin_amdgcn_mfma_f32_16x16x32_bf16(a1, b1, acc[(M0)+1][1], 0, 0, 0);       \
  acc[(M0)+1][2] = __builtin_amdgcn_mfma_f32_16x16x32_bf16(a1, b2, acc[(M0)+1][2], 0, 0, 0);       \
  acc[(M0)+1][3] = __builtin_amdgcn_mfma_f32_16x16x32_bf16(a1, b3, acc[(M0)+1][3], 0, 0, 0);       \
  acc[(M0)+2][0] = __builtin_amdgcn_mfma_f32_16x16x32_bf16(a2, b0, acc[(M0)+2][0], 0, 0, 0);       \
  acc[(M0)+2][1] = __builtin_amdgcn_mfma_f32_16x16x32_bf16(a2, b1, acc[(M0)+2][1], 0, 0, 0);       \
  acc[(M0)+2][2] = __builtin_amdgcn_mfma_f32_16x16x32_bf16(a2, b2, acc[(M0)+2][2], 0, 0, 0);       \
  acc[(M0)+2][3] = __builtin_amdgcn_mfma_f32_16x16x32_bf16(a2, b3, acc[(M0)+2][3], 0, 0, 0);       \
  acc[(M0)+3][0] = __builtin_amdgcn_mfma_f32_16x16x32_bf16(a3, b0, acc[(M0)+3][0], 0, 0, 0);       \
  acc[(M0)+3][1] = __builtin_amdgcn_mfma_f32_16x16x32_bf16(a3, b1, acc[(M0)+3][1], 0, 0, 0);       \
  acc[(M0)+3][2] = __builtin_amdgcn_mfma_f32_16x16x32_bf16(a3, b2, acc[(M0)+3][2], 0, 0, 0);       \
  acc[(M0)+3][3] = __builtin_amdgcn_mfma_f32_16x16x32_bf16(a3, b3, acc[(M0)+3][3], 0, 0, 0);       \
  __builtin_amdgcn_s_setprio(0)

  // ---- prologue: stage halves 0..4, publish h0,h1 (vmcnt: 10 out -> 6) ----
  STAGE(0); STAGE(1); STAGE(2); STAGE(3); STAGE(4);
  asm volatile("s_waitcnt vmcnt(6)" ::: "memory");
  __builtin_amdgcn_s_barrier();

#pragma unroll 1
  for (int kt = 0; kt < NT; ++kt) {
    int p = kt & 1;
    int hb = kt * 4 + 5;
    short8 a0, a1, a2, a3, b0, b1, b2, b3;
    // ---- phase 0: kh=0, mf 0-3 (+ B frags kh=0) ----
    LDA(a0, 0, 0, p); LDA(a1, 1, 0, p); LDA(a2, 2, 0, p); LDA(a3, 3, 0, p);
    LDB(b0, 0, 0, p); LDB(b1, 1, 0, p); LDB(b2, 2, 0, p); LDB(b3, 3, 0, p);
    STAGE(hb);
    __builtin_amdgcn_s_barrier();
    asm volatile("s_waitcnt lgkmcnt(0)" ::: "memory");
    MM16(0);
    __builtin_amdgcn_s_barrier();
    // ---- phase 1: kh=0, mf 4-7; reuse b0-b3 ----
    LDA(a0, 4, 0, p); LDA(a1, 5, 0, p); LDA(a2, 6, 0, p); LDA(a3, 7, 0, p);
    STAGE(hb + 1);
    __builtin_amdgcn_s_barrier();
    asm volatile("s_waitcnt lgkmcnt(0)" ::: "memory");
    MM16(4);
    if (kt == NT - 1) asm volatile("s_waitcnt vmcnt(0)" ::: "memory");
    else              asm volatile("s_waitcnt vmcnt(6)" ::: "memory");
    __builtin_amdgcn_s_barrier();
    // ---- phase 2: kh=1, mf 0-3 (+ B frags kh=1) ----
    LDA(a0, 0, 1, p); LDA(a1, 1, 1, p); LDA(a2, 2, 1, p); LDA(a3, 3, 1, p);
    LDB(b0, 0, 1, p); LDB(b1, 1, 1, p); LDB(b2, 2, 1, p); LDB(b3, 3, 1, p);
    STAGE(hb + 2);
    __builtin_amdgcn_s_barrier();
    asm volatile("s_waitcnt lgkmcnt(0)" ::: "memory");
    MM16(0);
    __builtin_amdgcn_s_barrier();
    // ---- phase 3: kh=1, mf 4-7 ----
    LDA(a0, 4, 1, p); LDA(a1, 5, 1, p); LDA(a2, 6, 1, p); LDA(a3, 7, 1, p);
    STAGE(hb + 3);
    __builtin_amdgcn_s_barrier();
    asm volatile("s_waitcnt lgkmcnt(0)" ::: "memory");
    MM16(4);
    if (kt == NT - 2)     asm volatile("s_waitcnt vmcnt(4)" ::: "memory");
    else if (kt < NT - 2) asm volatile("s_waitcnt vmcnt(6)" ::: "memory");
    __builtin_amdgcn_s_barrier();
  }
#undef STAGE
#undef LDA
#undef LDB
#undef MM16
}

// ---------------- GEMM1: qkv = x @ qkv_w^T + b; scatter q(scaled)/k/v --------
// Epilogue: stage C tile (bf16, bias+scale applied) in the now-dead 128 KiB
// LDS with a per-row chunk XOR swizzle, then store contiguous 32 KB slabs
// (one per h-group) with dwordx4 -> full-line HBM writes, 128 store instrs.
__global__ __launch_bounds__(512, 2) void gemm_qkv256(
    const u16* __restrict__ A, const u16* __restrict__ B,
    const float* __restrict__ qkvb, u16* __restrict__ qb,
    u16* __restrict__ kb, u16* __restrict__ vb) {
  __shared__ __align__(16) u16 lds[65536];   // 128 KiB
  f32x4 acc[8][4];
#pragma unroll
  for (int a = 0; a < 8; ++a)
#pragma unroll
    for (int c = 0; c < 4; ++c) acc[a][c] = (f32x4){0.f, 0.f, 0.f, 0.f};
  // XCD-chunked bijective swizzle (768 % 8 == 0): XCD k gets M-panels
  // [16k,16k+16) x all 6 N-blocks consecutively -> A-panel L2 reuse.
  int bid = blockIdx.x;
  int wg = (bid & 7) * 96 + (bid >> 3);
  int m0 = (wg / 6) * 256, n0 = (wg % 6) * 256;
  gemm256_core(A, B, m0, n0, lds, acc);

  int tid = threadIdx.x, wave = tid >> 6, lane = tid & 63;
  int wm = wave >> 2, wn = wave & 3;
  int cx = lane & 15, g = lane >> 4;

  // ---- stage C tile in LDS (all mainloop DMA drained; reads done at sync) --
  __syncthreads();
#pragma unroll
  for (int nf = 0; nf < 4; ++nf) {
    int cb = wn * 64 + nf * 16;              // tile-relative col base
    int cgl = n0 + cb + cx;                  // global col
    float bv = qkvb[cgl];
    float sc = ((cgl >> 9) == 0) ? 0.125f : 1.f;  // q-scale (uniform per instr)
#pragma unroll
    for (int mf = 0; mf < 8; ++mf) {
#pragma unroll
      for (int i = 0; i < 4; ++i) {
        int r = wm * 128 + mf * 16 + g * 4 + i;
        int c = cb + cx;
        int c16 = (c >> 3) ^ (((r >> 2) & 3) << 1);   // bank-spread swizzle
        lds[r * 256 + c16 * 8 + (c & 7)] = f2bf((acc[mf][nf][i] + bv) * sc);
      }
    }
  }
  __syncthreads();

  // ---- coalesced store: 4 h-group slabs, each 256n x 64d contiguous --------
  int b = m0 >> 8;                           // tile is one window (m0 % 256 == 0)
#pragma unroll
  for (int j = 0; j < 16; ++j) {
    const int hg = j >> 2;                   // compile-time per j
    int gcol = n0 + hg * 64;
    int which = gcol >> 9;
    int h = (gcol >> 6) & 7;
    u16* dst = (which == 0 ? qb : (which == 1 ? kb : vb)) +
               (size_t)(b * 8 + h) * 16384;
    int n = (j & 3) * 64 + (tid >> 3);
    int dc = tid & 7;
    int c16 = (hg * 8 + dc) ^ (((n >> 2) & 3) << 1);
    uint4 val = *(const uint4*)(lds + n * 256 + c16 * 8);
    *(uint4*)(dst + n * 64 + dc * 8) = val;
  }
}

// ---------------- GEMM2: out = attnout @ proj_w^T + proj_b (fp32 out) --------
__global__ __launch_bounds__(512, 2) void gemm_proj256(
    const u16* __restrict__ A, const u16* __restrict__ B,
    const float* __restrict__ pb, float* __restrict__ out) {
  __shared__ __align__(16) u16 lds[65536];   // 128 KiB
  f32x4 acc[8][4];
#pragma unroll
  for (int a = 0; a < 8; ++a)
#pragma unroll
    for (int c = 0; c < 4; ++c) acc[a][c] = (f32x4){0.f, 0.f, 0.f, 0.f};
  int bid = blockIdx.x;
  int wg = (bid & 7) * 32 + (bid >> 3);      // 256 % 8 == 0, bijective
  int m0 = (wg >> 1) * 256, n0 = (wg & 1) * 256;
  gemm256_core(A, B, m0, n0, lds, acc);
  int tid = threadIdx.x, wave = tid >> 6, lane = tid & 63;
  int wm = wave >> 2, wn = wave & 3;
  float bv[4];
#pragma unroll
  for (int nf = 0; nf < 4; ++nf)
    bv[nf] = pb[n0 + wn * 64 + nf * 16 + (lane & 15)];
  // mf,i outer / nf inner: the 64B chunks of each 128B line are issued in
  // consecutive store instructions -> L2 assembles full dirty lines.
#pragma unroll
  for (int mf = 0; mf < 8; ++mf) {
#pragma unroll
    for (int i = 0; i < 4; ++i) {
      int r = m0 + wm * 128 + mf * 16 + (lane >> 4) * 4 + i;
#pragma unroll
      for (int nf = 0; nf < 4; ++nf) {
        int c = n0 + wn * 64 + nf * 16 + (lane & 15);
        out[(size_t)r * 512 + c] = acc[mf][nf][i] + bv[nf];
      }
    }
  }
}

// ---------------- qconv: Q' = Q + conv15_n(Q), in place per (b,h) window -----
__global__ __launch_bounds__(256) void qconv(u16* __restrict__ qb,
                                             const float* __restrict__ pe_w) {
  __shared__ __align__(16) u16 Ql[256 * 72];
  __shared__ float w[15];
  int bh = blockIdx.x, h = bh & 7, tid = threadIdx.x;
  const uint4* src = (const uint4*)(qb + (size_t)bh * 16384);
#pragma unroll
  for (int it = 0; it < 8; ++it) {
    int idx = tid + it * 256;
    int row = idx >> 3, c = (idx & 7) * 8;
    *(uint4*)(Ql + row * 72 + c) = src[idx];
  }
  if (tid < 15) w[tid] = pe_w[h * 15 + tid] + (tid == 7 ? 1.f : 0.f);  // identity folded
  __syncthreads();
  int dg = (tid & 15) * 4, nb4 = tid >> 4;
  uint2* dst = (uint2*)(qb + (size_t)bh * 16384);
#pragma unroll
  for (int i = 0; i < 16; ++i) {
    int n = nb4 + i * 16;
    float a0 = 0.f, a1 = 0.f, a2 = 0.f, a3 = 0.f;
#pragma unroll
    for (int t = 0; t < 15; ++t) {
      int nn = n + t - 7;
      if (nn < 0 || nn > 255) continue;
      uint2 rv = *(const uint2*)(Ql + nn * 72 + dg);
      float wt = w[t];
      a0 += wt * bf2f(rv.x & 0xffff); a1 += wt * bf2f(rv.x >> 16);
      a2 += wt * bf2f(rv.y & 0xffff); a3 += wt * bf2f(rv.y >> 16);
    }
    uint2 pv;
    pv.x = (u32)f2bf(a0) | ((u32)f2bf(a1) << 16);
    pv.y = (u32)f2bf(a2) | ((u32)f2bf(a3) << 16);
    dst[(n * 64 + dg) >> 2] = pv;
  }
}

// ---------------- attention: 1 wg (512 thr) per (b,h); barrier-free loop -----
// LDS: KfPs 42K (Kf 32K + Ps 10K; doubles as Vtmp during staging) + Vf 32K +
// bias 3.8K = ~79.6K -> 2 wg/CU. Online softmax over 2 column halves keeps
// regs ~100 (no spill; launch_bounds(512,2) cannot force one).
__global__ __launch_bounds__(512, 2) void attn_win(
    const u16* __restrict__ qb, const u16* __restrict__ kb,
    const u16* __restrict__ vb, const float* __restrict__ pe_b,
    const float* __restrict__ rpb, u16* __restrict__ attnout) {
  __shared__ __align__(16) u16 KfPs[21504];   // [0,16384)=Kf, [16384,21504)=Ps
  __shared__ __align__(16) u16 Vf[16384];     // 32 frags (dt,km), fragment-ordered
  __shared__ float biasl[961];
  __shared__ float pebs;

  int bh = blockIdx.x, b = bh >> 3, h = bh & 7;
  int tid = threadIdx.x, wave = tid >> 6, lane = tid & 63;
  int cx = lane & 15, g = lane >> 4;

  const uint4* kg = (const uint4*)(kb + (size_t)bh * 16384);
  const uint4* vg = (const uint4*)(vb + (size_t)bh * 16384);

  // K prefetch into registers (Kf region is occupied by Vtmp until Vf built)
  uint4 kreg[4];
#pragma unroll
  for (int it = 0; it < 4; ++it) kreg[it] = kg[tid + it * 512];

  // ---- stage V rows -> Vtmp (stride 68, bank-spread) + bias ----
  u16* Vtmp = KfPs;
#pragma unroll
  for (int it = 0; it < 4; ++it) {
    int idx = tid + it * 512;
    uint4 v = vg[idx];
    int row = idx >> 3, c8 = (idx & 7) * 8;
    *(uint2*)(Vtmp + row * 68 + c8)     = make_uint2(v.x, v.y);
    *(uint2*)(Vtmp + row * 68 + c8 + 4) = make_uint2(v.z, v.w);
  }
  for (int i = tid; i < 961; i += 512) biasl[i] = rpb[i * 8 + h];
  if (tid == 0) pebs = pe_b[h];
  __syncthreads();

  // ---- build Vf fragments (transpose): frag(dt,km), lane holds V[m..m+7][d] --
#pragma unroll
  for (int it = 0; it < 4; ++it) {
    int o = tid + it * 512;
    int frag = o >> 6, lanep = o & 63;
    int d = (frag >> 3) * 16 + (lanep & 15);
    int mb = (frag & 7) * 32 + (lanep >> 4) * 8;
    uint4 pk;
    pk.x = (u32)Vtmp[(mb + 0) * 68 + d] | ((u32)Vtmp[(mb + 1) * 68 + d] << 16);
    pk.y = (u32)Vtmp[(mb + 2) * 68 + d] | ((u32)Vtmp[(mb + 3) * 68 + d] << 16);
    pk.z = (u32)Vtmp[(mb + 4) * 68 + d] | ((u32)Vtmp[(mb + 5) * 68 + d] << 16);
    pk.w = (u32)Vtmp[(mb + 6) * 68 + d] | ((u32)Vtmp[(mb + 7) * 68 + d] << 16);
    *(uint4*)(Vf + (frag * 64 + (lanep ^ (frag & 7))) * 8) = pk;
  }
  __syncthreads();

  // ---- write K fragments from registers ----
  u16* Kf = KfPs;
#pragma unroll
  for (int it = 0; it < 4; ++it) {
    int idx = tid + it * 512;
    int n = idx >> 3, k8 = idx & 7;
    int frag = (n >> 4) * 2 + (k8 >> 2);
    int lanep = (n & 15) + 16 * (k8 & 3);
    *(uint4*)(Kf + (frag * 64 + (lanep ^ (frag & 7))) * 8) = kreg[it];
  }
  __syncthreads();   // last barrier — main loop is barrier-free

  u16* Psw = KfPs + 16384 + wave * 640;
  const u16* qgb = qb + (size_t)bh * 16384;

  for (int it2 = 0; it2 < 2; ++it2) {
    int qbase = it2 * 128 + wave * 16;
    const u16* qg = qgb + qbase * 64;
    short8 qf0 = *(const short8*)(qg + cx * 64 + g * 8);
    short8 qf1 = *(const short8*)(qg + cx * 64 + 32 + g * 8);

    float m_run[4] = {-1e30f, -1e30f, -1e30f, -1e30f};
    float l_run[4] = {0.f, 0.f, 0.f, 0.f};
    f32x4 oacc[4];
#pragma unroll
    for (int dt = 0; dt < 4; ++dt) oacc[dt] = (f32x4){0.f, 0.f, 0.f, 0.f};

#pragma unroll
    for (int c = 0; c < 2; ++c) {
      // ---- QK^T over this 128-column half ----
      f32x4 acc[8];
#pragma unroll
      for (int mt = 0; mt < 8; ++mt) acc[mt] = (f32x4){0.f, 0.f, 0.f, 0.f};
#pragma unroll
      for (int mt = 0; mt < 8; ++mt) {
        int fr = (c * 8 + mt) * 2;
        short8 k0 = *(const short8*)(Kf + fragaddr(fr, lane));
        short8 k1 = *(const short8*)(Kf + fragaddr(fr + 1, lane));
        acc[mt] = __builtin_amdgcn_mfma_f32_16x16x32_bf16(qf0, k0, acc[mt], 0, 0, 0);
        acc[mt] = __builtin_amdgcn_mfma_f32_16x16x32_bf16(qf1, k1, acc[mt], 0, 0, 0);
      }

      // ---- bias + online softmax update (in-wave, no barriers) ----
      float alpha4[4];
#pragma unroll
      for (int i = 0; i < 4; ++i) {
        int qtok = qbase + g * 4 + i;
        int bbase = ((qtok >> 4) - c * 8 + 15) * 31 + (qtok & 15) - cx + 15;
#pragma unroll
        for (int mt = 0; mt < 8; ++mt) acc[mt][i] += pebs + biasl[bbase - 31 * mt];
        float mx = acc[0][i];
#pragma unroll
        for (int mt = 1; mt < 8; ++mt) mx = fmaxf(mx, acc[mt][i]);
        mx = fmaxf(mx, __shfl_xor(mx, 1));
        mx = fmaxf(mx, __shfl_xor(mx, 2));
        mx = fmaxf(mx, __shfl_xor(mx, 4));
        mx = fmaxf(mx, __shfl_xor(mx, 8));
        float mnew = fmaxf(m_run[i], mx);
        float al = __expf(m_run[i] - mnew);
        float s = 0.f;
#pragma unroll
        for (int mt = 0; mt < 8; ++mt) {
          float e = __expf(acc[mt][i] - mnew);
          acc[mt][i] = e; s += e;
        }
        s += __shfl_xor(s, 1);
        s += __shfl_xor(s, 2);
        s += __shfl_xor(s, 4);
        s += __shfl_xor(s, 8);
        l_run[i] = l_run[i] * al + s;
        m_run[i] = mnew;
        alpha4[i] = al;
      }
#pragma unroll
      for (int dt = 0; dt < 4; ++dt)
#pragma unroll
        for (int i = 0; i < 4; ++i) oacc[dt][i] *= alpha4[i];

      // ---- PV via per-wave scratch (in-wave LDS ordering) ----
#pragma unroll
      for (int kk = 0; kk < 4; ++kk) {
#pragma unroll
        for (int t2 = 0; t2 < 2; ++t2)
#pragma unroll
          for (int i = 0; i < 4; ++i)
            Psw[(g * 4 + i) * 40 + t2 * 16 + cx] = f2bf(acc[kk * 2 + t2][i]);
        short8 pa = *(const short8*)(Psw + cx * 40 + g * 8);
#pragma unroll
        for (int dt = 0; dt < 4; ++dt) {
          short8 vf = *(const short8*)(Vf + fragaddr(dt * 8 + c * 4 + kk, lane));
          oacc[dt] = __builtin_amdgcn_mfma_f32_16x16x32_bf16(pa, vf, oacc[dt], 0, 0, 0);
        }
      }
    }

    // ---- epilogue: normalize + store ----
    float inv4[4];
#pragma unroll
    for (int i = 0; i < 4; ++i) inv4[i] = 1.f / l_run[i];
#pragma unroll
    for (int dt = 0; dt < 4; ++dt)
#pragma unroll
      for (int i = 0; i < 4; ++i)
        attnout[((size_t)b * 256 + qbase + g * 4 + i) * 512 + h * 64 + dt * 16 + cx]
            = f2bf(oacc[dt][i] * inv4[i]);
  }
}

extern "C" void kernel_launch(void* const* d_in, const int* in_sizes, int n_in,
                              void* d_out, int out_size, void* d_ws, size_t ws_size,
                              hipStream_t stream) {
  const float* x      = (const float*)d_in[0];
  const float* qkv_w  = (const float*)d_in[1];
  const float* qkv_b  = (const float*)d_in[2];
  const float* pe_w   = (const float*)d_in[3];
  const float* pe_b   = (const float*)d_in[4];
  const float* rpb    = (const float*)d_in[5];
  const float* proj_w = (const float*)d_in[6];
  const float* proj_b = (const float*)d_in[7];
  float* out = (float*)d_out;
  char* ws = (char*)d_ws;

  size_t off = 0;
  u16* xbf = (u16*)(ws + off); off += (size_t)16777216 * 2;  // also attnout
  u16* w1  = (u16*)(ws + off); off += (size_t)786432 * 2;
  u16* w2  = (u16*)(ws + off); off += (size_t)262144 * 2;
  u16* qb  = (u16*)(ws + off); off += (size_t)16777216 * 2;
  u16* kb  = (u16*)(ws + off); off += (size_t)16777216 * 2;
  u16* vb  = (u16*)(ws + off); off += (size_t)16777216 * 2;

  hipLaunchKernelGGL(cvt_all, dim3(17408), dim3(256), 0, stream,
                     x, qkv_w, proj_w, xbf, w1, w2);
  hipLaunchKernelGGL(gemm_qkv256, dim3(768), dim3(512), 0, stream,
                     xbf, w1, qkv_b, qb, kb, vb);
  hipLaunchKernelGGL(qconv, dim3(1024), dim3(256), 0, stream, qb, pe_w);
  hipLaunchKernelGGL(attn_win, dim3(1024), dim3(512), 0, stream,
                     qb, kb, vb, pe_b, rpb, xbf);
  hipLaunchKernelGGL(gemm_proj256, dim3(256), dim3(512), 0, stream,
                     xbf, w2, proj_b, out);
}

// Round 3
// 294.041 us; speedup vs baseline: 1.2397x; 1.1014x over previous
//
#include <hip/hip_runtime.h>

// WindowAttention: x(128,256,512) -> qkv -> windowed attn (epeg conv folded
// into Q; barrier-free main loop, swapped-QK^T lane-local online softmax) -> proj.
//
// GEMMs use the 256x256 8-phase schedule (T1 XCD-chunk + T2 both-sides LDS
// swizzle + T3/T4 counted-vmcnt pipeline + T5 setprio), BK=64, 8 waves,
// 128 KiB LDS double buffer, K=512 (NT=8 K-tiles).
// gemm_qkv epilogue: C-tile staged in LDS (reused post-loop), stored as
// contiguous 32KB (b,h,n,d) slabs with dwordx4 -> no partial-line writes.
// attn: QK^T computed swapped (mfma(K,Q) -> S^T) so each lane owns one
// q-token and 32 lane-local k-values: softmax reduce = local tree + 2 shfl,
// P->bf16 via v_cvt_pk_bf16_f32 + ds_write_b64 (T12-style).
//
// ws layout (bytes):
//   [0)          xbf   33,554,432  (x bf16; REUSED as attnout after gemm_qkv)
//   [33554432)   w1     1,572,864  (qkv_w bf16)
//   [35127296)   w2       524,288  (proj_w bf16)
//   [35651584)   qb    33,554,432  (q scaled (b,h,n,d); conv'd in place)
//   [69206016)   kb    33,554,432  ((b,h,m,d))
//   [102760448)  vb    33,554,432  (V row-major (b,h,n,d))

typedef unsigned short u16;
typedef unsigned int u32;
typedef __attribute__((ext_vector_type(8))) short short8;   // 8 bf16 (4 VGPRs)
typedef __attribute__((ext_vector_type(4))) float f32x4;

__device__ __forceinline__ u16 f2bf(float f) {
  union { float f; u32 u; } v; v.f = f;
  return (u16)((v.u + 0x7FFFu + ((v.u >> 16) & 1u)) >> 16);  // RNE
}
__device__ __forceinline__ float bf2f(u16 s) {
  union { u32 u; float f; } v; v.u = ((u32)s) << 16;
  return v.f;
}
__device__ __forceinline__ u32 cvtpk(float lo, float hi) {   // RNE pack 2xbf16
  u32 r;
  asm("v_cvt_pk_bf16_f32 %0, %1, %2" : "=v"(r) : "v"(lo), "v"(hi));
  return r;
}

__device__ __forceinline__ void gl2lds16(const u16* g, u16* l) {
  __builtin_amdgcn_global_load_lds((const __attribute__((address_space(1))) void*)g,
                                   (__attribute__((address_space(3))) void*)l, 16, 0, 0);
}

// fragment cell address (u16 units) with bank-spreading XOR swizzle (attn)
__device__ __forceinline__ int fragaddr(int frag, int lane) {
  return (frag * 64 + (lane ^ (frag & 7))) * 8;
}

// ---------------- fp32 -> bf16 conversion ------------------------------------
__global__ __launch_bounds__(256) void cvt_all(
    const float* __restrict__ x, const float* __restrict__ w1f,
    const float* __restrict__ w2f, u16* __restrict__ xo,
    u16* __restrict__ w1o, u16* __restrict__ w2o) {
  const int NX = 4194304, NW1 = 196608, NW2 = 65536;
  int i = blockIdx.x * 256 + threadIdx.x;
  const float* src; u16* dst; int j;
  if (i < NX)                  { src = x;   dst = xo;  j = i; }
  else if (i < NX + NW1)       { src = w1f; dst = w1o; j = i - NX; }
  else if (i < NX + NW1 + NW2) { src = w2f; dst = w2o; j = i - NX - NW1; }
  else return;
  float4 f = ((const float4*)src)[j];
  uint2 o;
  o.x = (u32)f2bf(f.x) | ((u32)f2bf(f.y) << 16);
  o.y = (u32)f2bf(f.z) | ((u32)f2bf(f.w) << 16);
  ((uint2*)dst)[j] = o;
}

// ---------------- 256x256 8-phase GEMM core: C = A[256x512] * B[256x512]^T ---
// (unchanged from round 2 — see comments there)
__device__ __forceinline__ void gemm256_core(
    const u16* __restrict__ A, const u16* __restrict__ B,
    int m0, int n0, u16* lds, f32x4 acc[8][4]) {
  const int NT = 8;                       // K = 512, BK = 64
  int tid = threadIdx.x, wave = tid >> 6, lane = tid & 63;
  int wm = wave >> 2, wn = wave & 3;

  int ch0 = tid, ch1 = tid + 512;
  int row0 = ch0 >> 2, row1 = ch1 >> 2;
  int cg0 = (ch0 & 3) ^ (row0 & 3) ^ ((row0 >> 2) & 3);
  int cg1 = (ch1 & 3) ^ (row1 & 3) ^ ((row1 >> 2) & 3);
  const u16* Ag0 = A + (size_t)(m0 + row0) * 512 + cg0 * 8;
  const u16* Ag1 = A + (size_t)(m0 + row1) * 512 + cg1 * 8;
  const u16* Bg0 = B + (size_t)(n0 + row0) * 512 + cg0 * 8;
  const u16* Bg1 = B + (size_t)(n0 + row1) * 512 + cg1 * 8;
  int ldsu0 = wave * 64 * 8;              // HW adds lane*16B
  int ldsu1 = (512 + wave * 64) * 8;

  int frag_off = (lane & 15) * 32 +
                 (((lane >> 4) ^ (lane & 3) ^ ((lane >> 2) & 3)) << 3);
  int abase = wm * 4096 + frag_off;        // + mf*512 + kh*16384 + p*32768
  int bbase = 8192 + wn * 2048 + frag_off; // + nf*512 + kh*16384 + p*32768

#define STAGE(h)                                                             \
  do {                                                                       \
    if ((h) < NT * 4) {                                                      \
      int T_ = (h) >> 2, kh_ = ((h) >> 1) & 1, isB_ = (h) & 1;               \
      int ko_ = T_ * 64 + kh_ * 32;                                          \
      u16* d_ = lds + (T_ & 1) * 32768 + kh_ * 16384 + isB_ * 8192;          \
      gl2lds16((isB_ ? Bg0 : Ag0) + ko_, d_ + ldsu0);                        \
      gl2lds16((isB_ ? Bg1 : Ag1) + ko_, d_ + ldsu1);                        \
    }                                                                        \
  } while (0)

#define LDA(dst, mf, kh, p)                                                  \
  dst = *(const short8*)(lds + (p) * 32768 + (kh) * 16384 + abase + (mf) * 512)
#define LDB(dst, nf, kh, p)                                                  \
  dst = *(const short8*)(lds + (p) * 32768 + (kh) * 16384 + bbase + (nf) * 512)

#define MM16(M0)                                                                                   \
  __builtin_amdgcn_s_setprio(1);                                                                   \
  acc[(M0)+0][0] = __builtin_amdgcn_mfma_f32_16x16x32_bf16(a0, b0, acc[(M0)+0][0], 0, 0, 0);       \
  acc[(M0)+0][1] = __builtin_amdgcn_mfma_f32_16x16x32_bf16(a0, b1, acc[(M0)+0][1], 0, 0, 0);       \
  acc[(M0)+0][2] = __builtin_amdgcn_mfma_f32_16x16x32_bf16(a0, b2, acc[(M0)+0][2], 0, 0, 0);       \
  acc[(M0)+0][3] = __builtin_amdgcn_mfma_f32_16x16x32_bf16(a0, b3, acc[(M0)+0][3], 0, 0, 0);       \
  acc[(M0)+1][0] = __builtin_amdgcn_mfma_f32_16x16x32_bf16(a1, b0, acc[(M0)+1][0], 0, 0, 0);       \
  acc[(M0)+1][1] = __builtin_amdgcn_mfma_f32_16x16x32_bf16(a1, b1, acc[(M0)+1][1], 0, 0, 0);       \
  acc[(M0)+1][2] = __builtin_amdgcn_mfma_f32_16x16x32_bf16(a1, b2, acc[(M0)+1][2], 0, 0, 0);       \
  acc[(M0)+1][3] = __builtin_amdgcn_mfma_f32_16x16x32_bf16(a1, b3, acc[(M0)+1][3], 0, 0, 0);       \
  acc[(M0)+2][0] = __builtin_amdgcn_mfma_f32_16x16x32_bf16(a2, b0, acc[(M0)+2][0], 0, 0, 0);       \
  acc[(M0)+2][1] = __builtin_amdgcn_mfma_f32_16x16x32_bf16(a2, b1, acc[(M0)+2][1], 0, 0, 0);       \
  acc[(M0)+2][2] = __builtin_amdgcn_mfma_f32_16x16x32_bf16(a2, b2, acc[(M0)+2][2], 0, 0, 0);       \
  acc[(M0)+2][3] = __builtin_amdgcn_mfma_f32_16x16x32_bf16(a2, b3, acc[(M0)+2][3], 0, 0, 0);       \
  acc[(M0)+3][0] = __builtin_amdgcn_mfma_f32_16x16x32_bf16(a3, b0, acc[(M0)+3][0], 0, 0, 0);       \
  acc[(M0)+3][1] = __builtin_amdgcn_mfma_f32_16x16x32_bf16(a3, b1, acc[(M0)+3][1], 0, 0, 0);       \
  acc[(M0)+3][2] = __builtin_amdgcn_mfma_f32_16x16x32_bf16(a3, b2, acc[(M0)+3][2], 0, 0, 0);       \
  acc[(M0)+3][3] = __builtin_amdgcn_mfma_f32_16x16x32_bf16(a3, b3, acc[(M0)+3][3], 0, 0, 0);       \
  __builtin_amdgcn_s_setprio(0)

  STAGE(0); STAGE(1); STAGE(2); STAGE(3); STAGE(4);
  asm volatile("s_waitcnt vmcnt(6)" ::: "memory");
  __builtin_amdgcn_s_barrier();

#pragma unroll 1
  for (int kt = 0; kt < NT; ++kt) {
    int p = kt & 1;
    int hb = kt * 4 + 5;
    short8 a0, a1, a2, a3, b0, b1, b2, b3;
    LDA(a0, 0, 0, p); LDA(a1, 1, 0, p); LDA(a2, 2, 0, p); LDA(a3, 3, 0, p);
    LDB(b0, 0, 0, p); LDB(b1, 1, 0, p); LDB(b2, 2, 0, p); LDB(b3, 3, 0, p);
    STAGE(hb);
    __builtin_amdgcn_s_barrier();
    asm volatile("s_waitcnt lgkmcnt(0)" ::: "memory");
    MM16(0);
    __builtin_amdgcn_s_barrier();
    LDA(a0, 4, 0, p); LDA(a1, 5, 0, p); LDA(a2, 6, 0, p); LDA(a3, 7, 0, p);
    STAGE(hb + 1);
    __builtin_amdgcn_s_barrier();
    asm volatile("s_waitcnt lgkmcnt(0)" ::: "memory");
    MM16(4);
    if (kt == NT - 1) asm volatile("s_waitcnt vmcnt(0)" ::: "memory");
    else              asm volatile("s_waitcnt vmcnt(6)" ::: "memory");
    __builtin_amdgcn_s_barrier();
    LDA(a0, 0, 1, p); LDA(a1, 1, 1, p); LDA(a2, 2, 1, p); LDA(a3, 3, 1, p);
    LDB(b0, 0, 1, p); LDB(b1, 1, 1, p); LDB(b2, 2, 1, p); LDB(b3, 3, 1, p);
    STAGE(hb + 2);
    __builtin_amdgcn_s_barrier();
    asm volatile("s_waitcnt lgkmcnt(0)" ::: "memory");
    MM16(0);
    __builtin_amdgcn_s_barrier();
    LDA(a0, 4, 1, p); LDA(a1, 5, 1, p); LDA(a2, 6, 1, p); LDA(a3, 7, 1, p);
    STAGE(hb + 3);
    __builtin_amdgcn_s_barrier();
    asm volatile("s_waitcnt lgkmcnt(0)" ::: "memory");
    MM16(4);
    if (kt == NT - 2)     asm volatile("s_waitcnt vmcnt(4)" ::: "memory");
    else if (kt < NT - 2) asm volatile("s_waitcnt vmcnt(6)" ::: "memory");
    __builtin_amdgcn_s_barrier();
  }
#undef STAGE
#undef LDA
#undef LDB
#undef MM16
}

// ---------------- GEMM1: qkv = x @ qkv_w^T + b; scatter q(scaled)/k/v --------
__global__ __launch_bounds__(512, 2) void gemm_qkv256(
    const u16* __restrict__ A, const u16* __restrict__ B,
    const float* __restrict__ qkvb, u16* __restrict__ qb,
    u16* __restrict__ kb, u16* __restrict__ vb) {
  __shared__ __align__(16) u16 lds[65536];   // 128 KiB
  f32x4 acc[8][4];
#pragma unroll
  for (int a = 0; a < 8; ++a)
#pragma unroll
    for (int c = 0; c < 4; ++c) acc[a][c] = (f32x4){0.f, 0.f, 0.f, 0.f};
  int bid = blockIdx.x;
  int wg = (bid & 7) * 96 + (bid >> 3);
  int m0 = (wg / 6) * 256, n0 = (wg % 6) * 256;
  gemm256_core(A, B, m0, n0, lds, acc);

  int tid = threadIdx.x, wave = tid >> 6, lane = tid & 63;
  int wm = wave >> 2, wn = wave & 3;
  int cx = lane & 15, g = lane >> 4;

  __syncthreads();
#pragma unroll
  for (int nf = 0; nf < 4; ++nf) {
    int cb = wn * 64 + nf * 16;              // tile-relative col base
    int cgl = n0 + cb + cx;                  // global col
    float bv = qkvb[cgl];
    float sc = ((cgl >> 9) == 0) ? 0.125f : 1.f;  // q-scale (uniform per instr)
#pragma unroll
    for (int mf = 0; mf < 8; ++mf) {
#pragma unroll
      for (int i = 0; i < 4; ++i) {
        int r = wm * 128 + mf * 16 + g * 4 + i;
        int c = cb + cx;
        int c16 = (c >> 3) ^ (((r >> 2) & 3) << 1);   // bank-spread swizzle
        lds[r * 256 + c16 * 8 + (c & 7)] = f2bf((acc[mf][nf][i] + bv) * sc);
      }
    }
  }
  __syncthreads();

  int b = m0 >> 8;
#pragma unroll
  for (int j = 0; j < 16; ++j) {
    const int hg = j >> 2;
    int gcol = n0 + hg * 64;
    int which = gcol >> 9;
    int h = (gcol >> 6) & 7;
    u16* dst = (which == 0 ? qb : (which == 1 ? kb : vb)) +
               (size_t)(b * 8 + h) * 16384;
    int n = (j & 3) * 64 + (tid >> 3);
    int dc = tid & 7;
    int c16 = (hg * 8 + dc) ^ (((n >> 2) & 3) << 1);
    uint4 val = *(const uint4*)(lds + n * 256 + c16 * 8);
    *(uint4*)(dst + n * 64 + dc * 8) = val;
  }
}

// ---------------- GEMM2: out = attnout @ proj_w^T + proj_b (fp32 out) --------
__global__ __launch_bounds__(512, 2) void gemm_proj256(
    const u16* __restrict__ A, const u16* __restrict__ B,
    const float* __restrict__ pb, float* __restrict__ out) {
  __shared__ __align__(16) u16 lds[65536];   // 128 KiB
  f32x4 acc[8][4];
#pragma unroll
  for (int a = 0; a < 8; ++a)
#pragma unroll
    for (int c = 0; c < 4; ++c) acc[a][c] = (f32x4){0.f, 0.f, 0.f, 0.f};
  int bid = blockIdx.x;
  int wg = (bid & 7) * 32 + (bid >> 3);      // 256 % 8 == 0, bijective
  int m0 = (wg >> 1) * 256, n0 = (wg & 1) * 256;
  gemm256_core(A, B, m0, n0, lds, acc);
  int tid = threadIdx.x, wave = tid >> 6, lane = tid & 63;
  int wm = wave >> 2, wn = wave & 3;
  float bv[4];
#pragma unroll
  for (int nf = 0; nf < 4; ++nf)
    bv[nf] = pb[n0 + wn * 64 + nf * 16 + (lane & 15)];
#pragma unroll
  for (int mf = 0; mf < 8; ++mf) {
#pragma unroll
    for (int i = 0; i < 4; ++i) {
      int r = m0 + wm * 128 + mf * 16 + (lane >> 4) * 4 + i;
#pragma unroll
      for (int nf = 0; nf < 4; ++nf) {
        int c = n0 + wn * 64 + nf * 16 + (lane & 15);
        out[(size_t)r * 512 + c] = acc[mf][nf][i] + bv[nf];
      }
    }
  }
}

// ---------------- qconv: Q' = Q + conv15_n(Q), in place per (b,h) window -----
__global__ __launch_bounds__(256) void qconv(u16* __restrict__ qb,
                                             const float* __restrict__ pe_w) {
  __shared__ __align__(16) u16 Ql[256 * 72];
  __shared__ float w[15];
  int bh = blockIdx.x, h = bh & 7, tid = threadIdx.x;
  const uint4* src = (const uint4*)(qb + (size_t)bh * 16384);
#pragma unroll
  for (int it = 0; it < 8; ++it) {
    int idx = tid + it * 256;
    int row = idx >> 3, c = (idx & 7) * 8;
    *(uint4*)(Ql + row * 72 + c) = src[idx];
  }
  if (tid < 15) w[tid] = pe_w[h * 15 + tid] + (tid == 7 ? 1.f : 0.f);  // identity folded
  __syncthreads();
  int dg = (tid & 15) * 4, nb4 = tid >> 4;
  uint2* dst = (uint2*)(qb + (size_t)bh * 16384);
#pragma unroll
  for (int i = 0; i < 16; ++i) {
    int n = nb4 + i * 16;
    float a0 = 0.f, a1 = 0.f, a2 = 0.f, a3 = 0.f;
#pragma unroll
    for (int t = 0; t < 15; ++t) {
      int nn = n + t - 7;
      if (nn < 0 || nn > 255) continue;
      uint2 rv = *(const uint2*)(Ql + nn * 72 + dg);
      float wt = w[t];
      a0 += wt * bf2f(rv.x & 0xffff); a1 += wt * bf2f(rv.x >> 16);
      a2 += wt * bf2f(rv.y & 0xffff); a3 += wt * bf2f(rv.y >> 16);
    }
    uint2 pv;
    pv.x = (u32)f2bf(a0) | ((u32)f2bf(a1) << 16);
    pv.y = (u32)f2bf(a2) | ((u32)f2bf(a3) << 16);
    dst[(n * 64 + dg) >> 2] = pv;
  }
}

// ---------------- attention: 1 wg (512 thr) per (b,h); barrier-free loop -----
// Swapped QK^T: acc[mt] = mfma(K,Q) holds S^T -> lane (cx,g) owns q=qbase+cx
// with 32 lane-local k-values (k = c*128 + mt*16 + g*4 + i). Softmax reduce =
// 31 local max/sum + shfl_xor(16,32). m/l scalar per lane. P packed with
// v_cvt_pk_bf16_f32 (k-consecutive in-lane) -> 2x ds_write_b64 per mt-pair;
// PV A-frag read (row=cx=q) unchanged. alpha/1-l shfl'd back to row domain.
__global__ __launch_bounds__(512, 2) void attn_win(
    const u16* __restrict__ qb, const u16* __restrict__ kb,
    const u16* __restrict__ vb, const float* __restrict__ pe_b,
    const float* __restrict__ rpb, u16* __restrict__ attnout) {
  __shared__ __align__(16) u16 KfPs[21504];   // [0,16384)=Kf, [16384,21504)=Ps
  __shared__ __align__(16) u16 Vf[16384];     // 32 frags (dt,km), fragment-ordered
  __shared__ float biasl[961];

  int bh = blockIdx.x, b = bh >> 3, h = bh & 7;
  int tid = threadIdx.x, wave = tid >> 6, lane = tid & 63;
  int cx = lane & 15, g = lane >> 4;

  const uint4* kg = (const uint4*)(kb + (size_t)bh * 16384);
  const uint4* vg = (const uint4*)(vb + (size_t)bh * 16384);
  const u16* qgb = qb + (size_t)bh * 16384;

  // Q fragments for both it2 hoisted: latency hides under staging barriers
  short8 qfr0a = *(const short8*)(qgb + (0 * 128 + wave * 16 + cx) * 64 + g * 8);
  short8 qfr0b = *(const short8*)(qgb + (0 * 128 + wave * 16 + cx) * 64 + 32 + g * 8);
  short8 qfr1a = *(const short8*)(qgb + (1 * 128 + wave * 16 + cx) * 64 + g * 8);
  short8 qfr1b = *(const short8*)(qgb + (1 * 128 + wave * 16 + cx) * 64 + 32 + g * 8);

  // K prefetch into registers (Kf region is occupied by Vtmp until Vf built)
  uint4 kreg[4];
#pragma unroll
  for (int it = 0; it < 4; ++it) kreg[it] = kg[tid + it * 512];

  // ---- stage V rows -> Vtmp (stride 68, bank-spread) + bias (pe_b folded) ---
  u16* Vtmp = KfPs;
#pragma unroll
  for (int it = 0; it < 4; ++it) {
    int idx = tid + it * 512;
    uint4 v = vg[idx];
    int row = idx >> 3, c8 = (idx & 7) * 8;
    *(uint2*)(Vtmp + row * 68 + c8)     = make_uint2(v.x, v.y);
    *(uint2*)(Vtmp + row * 68 + c8 + 4) = make_uint2(v.z, v.w);
  }
  {
    float peb = pe_b[h];
    for (int i = tid; i < 961; i += 512) biasl[i] = rpb[i * 8 + h] + peb;
  }
  __syncthreads();

  // ---- build Vf fragments (transpose): frag(dt,km), lane holds V[m..m+7][d] --
#pragma unroll
  for (int it = 0; it < 4; ++it) {
    int o = tid + it * 512;
    int frag = o >> 6, lanep = o & 63;
    int d = (frag >> 3) * 16 + (lanep & 15);
    int mb = (frag & 7) * 32 + (lanep >> 4) * 8;
    uint4 pk;
    pk.x = (u32)Vtmp[(mb + 0) * 68 + d] | ((u32)Vtmp[(mb + 1) * 68 + d] << 16);
    pk.y = (u32)Vtmp[(mb + 2) * 68 + d] | ((u32)Vtmp[(mb + 3) * 68 + d] << 16);
    pk.z = (u32)Vtmp[(mb + 4) * 68 + d] | ((u32)Vtmp[(mb + 5) * 68 + d] << 16);
    pk.w = (u32)Vtmp[(mb + 6) * 68 + d] | ((u32)Vtmp[(mb + 7) * 68 + d] << 16);
    *(uint4*)(Vf + (frag * 64 + (lanep ^ (frag & 7))) * 8) = pk;
  }
  __syncthreads();

  // ---- write K fragments from registers ----
  u16* Kf = KfPs;
#pragma unroll
  for (int it = 0; it < 4; ++it) {
    int idx = tid + it * 512;
    int n = idx >> 3, k8 = idx & 7;
    int frag = (n >> 4) * 2 + (k8 >> 2);
    int lanep = (n & 15) + 16 * (k8 & 3);
    *(uint4*)(Kf + (frag * 64 + (lanep ^ (frag & 7))) * 8) = kreg[it];
  }
  __syncthreads();   // last barrier — main loop is barrier-free

  u16* Psw = KfPs + 16384 + wave * 640;

#pragma unroll
  for (int it2 = 0; it2 < 2; ++it2) {
    short8 qf0 = it2 ? qfr1a : qfr0a;
    short8 qf1 = it2 ? qfr1b : qfr0b;
    int qbase = it2 * 128 + wave * 16;

    float m_run = -1e30f, l_run = 0.f;
    f32x4 oacc[4];
#pragma unroll
    for (int dt = 0; dt < 4; ++dt) oacc[dt] = (f32x4){0.f, 0.f, 0.f, 0.f};

#pragma unroll
    for (int c = 0; c < 2; ++c) {
      // ---- QK^T (swapped): acc[mt] = S^T rows k, cols q=cx ----
      f32x4 acc[8];
#pragma unroll
      for (int mt = 0; mt < 8; ++mt) acc[mt] = (f32x4){0.f, 0.f, 0.f, 0.f};
      __builtin_amdgcn_s_setprio(1);
#pragma unroll
      for (int mt = 0; mt < 8; ++mt) {
        int fr = (c * 8 + mt) * 2;
        short8 k0 = *(const short8*)(Kf + fragaddr(fr, lane));
        short8 k1 = *(const short8*)(Kf + fragaddr(fr + 1, lane));
        acc[mt] = __builtin_amdgcn_mfma_f32_16x16x32_bf16(k0, qf0, acc[mt], 0, 0, 0);
        acc[mt] = __builtin_amdgcn_mfma_f32_16x16x32_bf16(k1, qf1, acc[mt], 0, 0, 0);
      }
      __builtin_amdgcn_s_setprio(0);

      // ---- bias add (lane-local k) ----
      // k = c*128 + mt*16 + g*4 + i ; q = qbase + cx
      int nb = (it2 * 8 + wave - c * 8 + 15) * 31 + cx - g * 4 + 15;
#pragma unroll
      for (int mt = 0; mt < 8; ++mt) {
        const float* bp = biasl + (nb - 31 * mt);
        acc[mt][0] += bp[0];  acc[mt][1] += bp[-1];
        acc[mt][2] += bp[-2]; acc[mt][3] += bp[-3];
      }

      // ---- online softmax: lane-local tree + 2 shfl ----
      float mx = fmaxf(fmaxf(acc[0][0], acc[0][1]), fmaxf(acc[0][2], acc[0][3]));
#pragma unroll
      for (int mt = 1; mt < 8; ++mt)
        mx = fmaxf(mx, fmaxf(fmaxf(acc[mt][0], acc[mt][1]),
                             fmaxf(acc[mt][2], acc[mt][3])));
      mx = fmaxf(mx, __shfl_xor(mx, 16));
      mx = fmaxf(mx, __shfl_xor(mx, 32));
      float mnew = fmaxf(m_run, mx);
      float al = __expf(m_run - mnew);
      float s = 0.f;
#pragma unroll
      for (int mt = 0; mt < 8; ++mt)
#pragma unroll
        for (int i = 0; i < 4; ++i) {
          float e = __expf(acc[mt][i] - mnew);
          acc[mt][i] = e; s += e;
        }
      s += __shfl_xor(s, 16);
      s += __shfl_xor(s, 32);
      l_run = l_run * al + s;
      m_run = mnew;

      // alpha back to row domain (oacc rows are q = g*4+i)
      float alr[4];
#pragma unroll
      for (int i = 0; i < 4; ++i) alr[i] = __shfl(al, g * 4 + i);
#pragma unroll
      for (int dt = 0; dt < 4; ++dt)
#pragma unroll
        for (int i = 0; i < 4; ++i) oacc[dt][i] *= alr[i];

      // ---- PV: pack P (k-consecutive in-lane) -> LDS -> A-frag read ----
#pragma unroll
      for (int kk = 0; kk < 4; ++kk) {
        // mt = 2kk (cols g*4..+3), 2kk+1 (cols 16+g*4..+3) of 32-wide k-chunk
        u32 w0 = cvtpk(acc[2 * kk][0], acc[2 * kk][1]);
        u32 w1 = cvtpk(acc[2 * kk][2], acc[2 * kk][3]);
        u32 w2 = cvtpk(acc[2 * kk + 1][0], acc[2 * kk + 1][1]);
        u32 w3 = cvtpk(acc[2 * kk + 1][2], acc[2 * kk + 1][3]);
        *(uint2*)(Psw + cx * 40 + g * 4)      = make_uint2(w0, w1);
        *(uint2*)(Psw + cx * 40 + 16 + g * 4) = make_uint2(w2, w3);
        short8 pa = *(const short8*)(Psw + cx * 40 + g * 8);
        __builtin_amdgcn_s_setprio(1);
#pragma unroll
        for (int dt = 0; dt < 4; ++dt) {
          short8 vf = *(const short8*)(Vf + fragaddr(dt * 8 + c * 4 + kk, lane));
          oacc[dt] = __builtin_amdgcn_mfma_f32_16x16x32_bf16(pa, vf, oacc[dt], 0, 0, 0);
        }
        __builtin_amdgcn_s_setprio(0);
      }
    }

    // ---- epilogue: normalize + store (1/l shfl'd to row domain) ----
    float inv = 1.f / l_run;
    float inv4[4];
#pragma unroll
    for (int i = 0; i < 4; ++i) inv4[i] = __shfl(inv, g * 4 + i);
#pragma unroll
    for (int dt = 0; dt < 4; ++dt)
#pragma unroll
      for (int i = 0; i < 4; ++i)
        attnout[((size_t)b * 256 + qbase + g * 4 + i) * 512 + h * 64 + dt * 16 + cx]
            = f2bf(oacc[dt][i] * inv4[i]);
  }
}

extern "C" void kernel_launch(void* const* d_in, const int* in_sizes, int n_in,
                              void* d_out, int out_size, void* d_ws, size_t ws_size,
                              hipStream_t stream) {
  const float* x      = (const float*)d_in[0];
  const float* qkv_w  = (const float*)d_in[1];
  const float* qkv_b  = (const float*)d_in[2];
  const float* pe_w   = (const float*)d_in[3];
  const float* pe_b   = (const float*)d_in[4];
  const float* rpb    = (const float*)d_in[5];
  const float* proj_w = (const float*)d_in[6];
  const float* proj_b = (const float*)d_in[7];
  float* out = (float*)d_out;
  char* ws = (char*)d_ws;

  size_t off = 0;
  u16* xbf = (u16*)(ws + off); off += (size_t)16777216 * 2;  // also attnout
  u16* w1  = (u16*)(ws + off); off += (size_t)786432 * 2;
  u16* w2  = (u16*)(ws + off); off += (size_t)262144 * 2;
  u16* qb  = (u16*)(ws + off); off += (size_t)16777216 * 2;
  u16* kb  = (u16*)(ws + off); off += (size_t)16777216 * 2;
  u16* vb  = (u16*)(ws + off); off += (size_t)16777216 * 2;

  hipLaunchKernelGGL(cvt_all, dim3(17408), dim3(256), 0, stream,
                     x, qkv_w, proj_w, xbf, w1, w2);
  hipLaunchKernelGGL(gemm_qkv256, dim3(768), dim3(512), 0, stream,
                     xbf, w1, qkv_b, qb, kb, vb);
  hipLaunchKernelGGL(qconv, dim3(1024), dim3(256), 0, stream, qb, pe_w);
  hipLaunchKernelGGL(attn_win, dim3(1024), dim3(512), 0, stream,
                     qb, kb, vb, pe_b, rpb, xbf);
  hipLaunchKernelGGL(gemm_proj256, dim3(256), dim3(512), 0, stream,
                     xbf, w2, proj_b, out);
}